// Round 11
// baseline (347.843 us; speedup 1.0000x reference)
//
#include <hip/hip_runtime.h>

// LoRALinear: out[8192,4096] = x @ W.T + 2.0*(x@A.T)@B.T = x @ (W + 2*B@A).T
// One bf16 MFMA GEMM, 256x256 tile, 8 waves, BK=64, R7's proven 4-phase
// schedule + stage stream + vmcnt(4)/tile, ported to 32x32x16 MFMA
// (2495 TF ubench vs 2075 for 16x16x32; half the MFMA instructions).

#define N_ROWS 8192
#define K_DIM  4096
#define N_COLS 4096
#define RANK   16
#define BK     64
#define NT     (K_DIM / BK)   // 64 K-tiles

#define XBLK ((N_ROWS * K_DIM / 4) / 256)   // 32768 blocks for x->bf16
#define WBLK ((N_COLS * K_DIM / 4) / 256)   // 16384 blocks for W_eff->bf16

typedef __bf16 bf16x8 __attribute__((ext_vector_type(8)));
typedef float  f32x16 __attribute__((ext_vector_type(16)));

__device__ __forceinline__ unsigned short f2bf(float f) {
  unsigned int u = __builtin_bit_cast(unsigned int, f);
  u += 0x7FFFu + ((u >> 16) & 1u);   // RNE
  return (unsigned short)(u >> 16);
}

// ---------------- fused conversion kernel ----------------

__global__ __launch_bounds__(256) void prep_kernel(const float* __restrict__ x,
                                                   const float* __restrict__ w,
                                                   const float* __restrict__ A,
                                                   const float* __restrict__ Bm,
                                                   unsigned short* __restrict__ xb,
                                                   unsigned short* __restrict__ wb) {
  const int b = blockIdx.x;
  if (b < XBLK) {
    size_t idx = (size_t)b * 256 + threadIdx.x;
    const float4 v = *reinterpret_cast<const float4*>(x + idx * 4);
    ushort4 r;
    r.x = f2bf(v.x); r.y = f2bf(v.y); r.z = f2bf(v.z); r.w = f2bf(v.w);
    *reinterpret_cast<ushort4*>(xb + idx * 4) = r;
  } else {
    size_t idx = (size_t)(b - XBLK) * 256 + threadIdx.x;
    int o  = (int)(idx >> 10);
    int ic = (int)(idx & 1023) << 2;
    const float4 wv = *reinterpret_cast<const float4*>(w + (size_t)o * K_DIM + ic);
    float a0 = wv.x, a1 = wv.y, a2 = wv.z, a3 = wv.w;
    float br[RANK];
#pragma unroll
    for (int r4 = 0; r4 < RANK / 4; ++r4) {
      const float4 bv = *reinterpret_cast<const float4*>(Bm + (size_t)o * RANK + r4 * 4);
      br[r4 * 4 + 0] = bv.x; br[r4 * 4 + 1] = bv.y;
      br[r4 * 4 + 2] = bv.z; br[r4 * 4 + 3] = bv.w;
    }
#pragma unroll
    for (int r = 0; r < RANK; ++r) {
      const float4 av = *reinterpret_cast<const float4*>(A + (size_t)r * K_DIM + ic);
      float b2 = br[r] * 2.0f;
      a0 += b2 * av.x; a1 += b2 * av.y; a2 += b2 * av.z; a3 += b2 * av.w;
    }
    ushort4 rr;
    rr.x = f2bf(a0); rr.y = f2bf(a1); rr.z = f2bf(a2); rr.w = f2bf(a3);
    *reinterpret_cast<ushort4*>(wb + (size_t)o * K_DIM + ic) = rr;
  }
}

// ---------------- GEMM ----------------
// LDS: A [buf][half][128 rows][64 k] bf16 at 0..64K; B same at 64K..128K.
// XOR swizzle within a half (16B granules): phys = logical ^ (row&7); staged
// via pre-swizzled global source (linear gload_lds dest), read w/ matching XOR.
// 32x32x16 geometry: wave (wm=wv>>2, wn=wv&3).
//   out row = mf*64 + wm*32 + rowCD   (mf 0..3; mf0-1 -> A-half0)
//   out col = nf*128 + wn*32 + colCD  (nf 0..1; nf == B-half)
//   A operand: lane holds row l&31, k-chunk (l>>5)*8 (per 16x16 family);
//   C/D: col = l&31, row = (reg&3) + 8*(reg>>2) + 4*(l>>5)  [m74/m101].
// Schedule/stage stream/waits identical to R7 (proven correct):
//  ph1: STG A1(t+1)->n; rd A mf0-1 + B nf0 (12); MFMA mf0-1 x nf0
//  ph2: STG B0(t+1)->n; rd B nf1 (4);            MFMA mf0-1 x nf1
//  ph3: STG A0(t+2)->c; rd A mf2-3 (8);          MFMA mf2-3 x nf1
//  ph4: STG B1(t+2)->c; (bE held);               MFMA mf2-3 x nf0; vmcnt(4)

__device__ __forceinline__ void gload_lds16(const void* g, void* l) {
  __builtin_amdgcn_global_load_lds(
      (__attribute__((address_space(1))) void*)g,
      (__attribute__((address_space(3))) void*)l, 16, 0, 0);
}

__global__ __launch_bounds__(512, 1) void gemm_bf16_r11(
    const unsigned short* __restrict__ xb, const unsigned short* __restrict__ wb,
    float* __restrict__ out) {
  __shared__ __align__(16) char smem[131072];

  const int t   = threadIdx.x;
  const int l   = t & 63;
  const int wv  = t >> 6;
  const int l31 = l & 31;
  const int l5  = l >> 5;     // 0..1
  const int wm  = wv >> 2;    // 0..1
  const int wn  = wv & 3;     // 0..3

  // XCD-aware bijective swizzle: 512 blocks % 8 == 0
  const int bid  = blockIdx.x;
  const int sbid = (bid & 7) * 64 + (bid >> 3);
  const int bm   = sbid >> 4;   // 0..31
  const int bn   = sbid & 15;   // 0..15

  // staging: thread t -> row t>>3 (0..63), swizzled col granule (as R7)
  const int srow = t >> 3;
  const int scol = ((t & 7) ^ ((t >> 3) & 7)) << 3;         // elements
  const unsigned short* gA = xb + (size_t)(bm * 256 + srow) * K_DIM + scol;
  const unsigned short* gB = wb + (size_t)(bn * 256 + srow) * K_DIM + scol;
  char* ldsA = smem + t * 16;
  char* ldsB = smem + 65536 + t * 16;

#define STG_A(hh, SRC, NB) do {                                                 \
    const unsigned short* _g = (SRC) + (size_t)((hh) * 128) * K_DIM;            \
    char* _l = ldsA + (NB) + (hh) * 16384;                                      \
    gload_lds16(_g, _l);                                                        \
    gload_lds16(_g + (size_t)64 * K_DIM, _l + 8192);                            \
  } while (0)
#define STG_B(hh, SRC, NB) do {                                                 \
    const unsigned short* _g = (SRC) + (size_t)((hh) * 128) * K_DIM;            \
    char* _l = ldsB + (NB) + (hh) * 16384;                                      \
    gload_lds16(_g, _l);                                                        \
    gload_lds16(_g + (size_t)64 * K_DIM, _l + 8192);                            \
  } while (0)

  // fragment read addressing: granule index = 2*kk + l5, XOR row&7 (= l&7)
  const int g0 = ((0 + l5) ^ (l & 7)) << 4;
  const int g1 = ((2 + l5) ^ (l & 7)) << 4;
  const int g2 = ((4 + l5) ^ (l & 7)) << 4;
  const int g3 = ((6 + l5) ^ (l & 7)) << 4;
  const int base_a = (wm * 32 + l31) * 128;            // + mf*8192 (+CB)
  const int base_b = 65536 + (wn * 32 + l31) * 128;    // + nf*16384 (+CB)

  bf16x8 aF[8];      // current A mf-pair: 2 mf x 4 kk
  bf16x8 bE[4];      // B nf0: read ph1, HELD through ph4
  bf16x8 bO[4];      // B nf1: read ph2, used ph2-ph3
  f32x16 acc[4][2];
#pragma unroll
  for (int m = 0; m < 4; ++m)
#pragma unroll
    for (int n = 0; n < 2; ++n)
#pragma unroll
      for (int e = 0; e < 16; ++e)
        acc[m][n][e] = 0.f;

#define RD_A01(CB_) do {                                                        \
    aF[0] = *(const bf16x8*)(smem + (CB_) + base_a + g0);                       \
    aF[1] = *(const bf16x8*)(smem + (CB_) + base_a + g1);                       \
    aF[2] = *(const bf16x8*)(smem + (CB_) + base_a + g2);                       \
    aF[3] = *(const bf16x8*)(smem + (CB_) + base_a + g3);                       \
    aF[4] = *(const bf16x8*)(smem + (CB_) + 8192 + base_a + g0);                \
    aF[5] = *(const bf16x8*)(smem + (CB_) + 8192 + base_a + g1);                \
    aF[6] = *(const bf16x8*)(smem + (CB_) + 8192 + base_a + g2);                \
    aF[7] = *(const bf16x8*)(smem + (CB_) + 8192 + base_a + g3);                \
  } while (0)
#define RD_A23(CB_) do {                                                        \
    aF[0] = *(const bf16x8*)(smem + (CB_) + 16384 + base_a + g0);               \
    aF[1] = *(const bf16x8*)(smem + (CB_) + 16384 + base_a + g1);               \
    aF[2] = *(const bf16x8*)(smem + (CB_) + 16384 + base_a + g2);               \
    aF[3] = *(const bf16x8*)(smem + (CB_) + 16384 + base_a + g3);               \
    aF[4] = *(const bf16x8*)(smem + (CB_) + 24576 + base_a + g0);               \
    aF[5] = *(const bf16x8*)(smem + (CB_) + 24576 + base_a + g1);               \
    aF[6] = *(const bf16x8*)(smem + (CB_) + 24576 + base_a + g2);               \
    aF[7] = *(const bf16x8*)(smem + (CB_) + 24576 + base_a + g3);               \
  } while (0)
#define RD_B(DST, CB_, HOFF) do {                                               \
    DST[0] = *(const bf16x8*)(smem + (CB_) + (HOFF) + base_b + g0);             \
    DST[1] = *(const bf16x8*)(smem + (CB_) + (HOFF) + base_b + g1);             \
    DST[2] = *(const bf16x8*)(smem + (CB_) + (HOFF) + base_b + g2);             \
    DST[3] = *(const bf16x8*)(smem + (CB_) + (HOFF) + base_b + g3);             \
  } while (0)

#define MFMA2(M0, NF, BF) do {                                                  \
    _Pragma("unroll")                                                           \
    for (int mi = 0; mi < 2; ++mi)                                              \
      _Pragma("unroll")                                                         \
      for (int kk = 0; kk < 4; ++kk)                                            \
        acc[(M0) + mi][(NF)] = __builtin_amdgcn_mfma_f32_32x32x16_bf16(         \
            aF[mi * 4 + kk], BF[kk], acc[(M0) + mi][(NF)], 0, 0, 0);            \
  } while (0)

#define PRE_LG() do {                                                           \
    __builtin_amdgcn_sched_barrier(0);                                          \
    __builtin_amdgcn_s_barrier();                                               \
    asm volatile("s_waitcnt lgkmcnt(0)");                                       \
    __builtin_amdgcn_sched_barrier(0);                                          \
    __builtin_amdgcn_s_setprio(1);                                              \
  } while (0)
#define PRE_NOLG() do {                                                         \
    __builtin_amdgcn_sched_barrier(0);                                          \
    __builtin_amdgcn_s_barrier();                                               \
    __builtin_amdgcn_sched_barrier(0);                                          \
    __builtin_amdgcn_s_setprio(1);                                              \
  } while (0)
#define POST() do {                                                             \
    __builtin_amdgcn_s_setprio(0);                                              \
    __builtin_amdgcn_sched_barrier(0);                                          \
    __builtin_amdgcn_s_barrier();                                               \
    __builtin_amdgcn_sched_barrier(0);                                          \
  } while (0)
#define POST_VM4() do {                                                         \
    __builtin_amdgcn_s_setprio(0);                                              \
    __builtin_amdgcn_sched_barrier(0);                                          \
    asm volatile("s_waitcnt vmcnt(4)");                                         \
    __builtin_amdgcn_s_barrier();                                               \
    __builtin_amdgcn_sched_barrier(0);                                          \
  } while (0)

#define TILE(CB, NB, T) do {                                                    \
    const int _t1 = ((T) + 1 < NT) ? (T) + 1 : NT - 1;                          \
    const int _t2 = ((T) + 2 < NT) ? (T) + 2 : NT - 1;                          \
    const unsigned short* _sA1 = gA + (size_t)_t1 * BK;                         \
    const unsigned short* _sB1 = gB + (size_t)_t1 * BK;                         \
    const unsigned short* _sA2 = gA + (size_t)_t2 * BK;                         \
    const unsigned short* _sB2 = gB + (size_t)_t2 * BK;                         \
    /* ph1: stage A1(t+1)->n; rd A mf0-1 + B nf0; MFMA mf0-1 x nf0 */           \
    STG_A(1, _sA1, NB);                                                         \
    RD_A01((CB)); RD_B(bE, (CB), 0);                                            \
    asm volatile("s_waitcnt lgkmcnt(8)");                                       \
    PRE_LG(); MFMA2(0, 0, bE); POST();                                          \
    /* ph2: stage B0(t+1)->n; rd B nf1; MFMA mf0-1 x nf1 */                     \
    STG_B(0, _sB1, NB);                                                         \
    RD_B(bO, (CB), 16384);                                                      \
    PRE_LG(); MFMA2(0, 1, bO); POST();                                          \
    /* ph3: stage A0(t+2)->c; rd A mf2-3; MFMA mf2-3 x nf1 */                   \
    STG_A(0, _sA2, CB);                                                         \
    RD_A23((CB));                                                               \
    PRE_LG(); MFMA2(2, 1, bO); POST();                                          \
    /* ph4: stage B1(t+2)->c; bE held; MFMA mf2-3 x nf0; vmcnt(4) */            \
    STG_B(1, _sB2, CB);                                                         \
    PRE_NOLG(); MFMA2(2, 0, bE); POST_VM4();                                    \
  } while (0)

  // ---- prologue: stage tile0 -> buf0 (8) + A0(1),B1(1) -> buf1 (4); vmcnt(4)
  STG_A(0, gA, 0); STG_A(1, gA, 0); STG_B(0, gB, 0); STG_B(1, gB, 0);
  {
    const unsigned short* _pA1 = gA + (size_t)BK;
    const unsigned short* _pB1 = gB + (size_t)BK;
    STG_A(0, _pA1, 32768);
    STG_B(1, _pB1, 32768);
  }
  __builtin_amdgcn_sched_barrier(0);
  asm volatile("s_waitcnt vmcnt(4)");
  __builtin_amdgcn_s_barrier();
  __builtin_amdgcn_sched_barrier(0);

#pragma nounroll
  for (int u = 0; u < NT / 2; ++u) {
    TILE(0, 32768, 2 * u);
    TILE(32768, 0, 2 * u + 1);
  }

  // ---- epilogue: C/D layout col=l&31, row=(reg&3)+8*(reg>>2)+4*(l>>5) ----
  const int orow = bm * 256 + wm * 32 + l5 * 4;
  const int ocol = bn * 256 + wn * 32 + l31;
#pragma unroll
  for (int mf = 0; mf < 4; ++mf)
#pragma unroll
    for (int nf = 0; nf < 2; ++nf)
#pragma unroll
      for (int reg = 0; reg < 16; ++reg) {
        const int row = orow + mf * 64 + (reg & 3) + 8 * (reg >> 2);
        out[(size_t)row * N_COLS + (ocol + nf * 128)] = acc[mf][nf][reg];
      }

#undef STG_A
#undef STG_B
#undef RD_A01
#undef RD_A23
#undef RD_B
#undef MFMA2
#undef PRE_LG
#undef PRE_NOLG
#undef POST
#undef POST_VM4
#undef TILE
}

// ---------------- exact fp32 fallback (ws too small) ----------------

__global__ __launch_bounds__(256) void fallback_kernel(const float* __restrict__ x,
                                                       const float* __restrict__ w,
                                                       const float* __restrict__ A,
                                                       const float* __restrict__ Bm,
                                                       float* __restrict__ out) {
  const int o    = blockIdx.x * 256 + threadIdx.x;
  const int nrow = blockIdx.y;
  float bro[RANK];
#pragma unroll
  for (int r = 0; r < RANK; ++r) bro[r] = Bm[(size_t)o * RANK + r] * 2.0f;
  float bacc = 0.f;
  float tacc[RANK];
#pragma unroll
  for (int r = 0; r < RANK; ++r) tacc[r] = 0.f;
  for (int k = 0; k < K_DIM; ++k) {
    float xv = x[(size_t)nrow * K_DIM + k];
    bacc += xv * w[(size_t)o * K_DIM + k];
#pragma unroll
    for (int r = 0; r < RANK; ++r) tacc[r] += xv * A[(size_t)r * K_DIM + k];
  }
  float res = bacc;
#pragma unroll
  for (int r = 0; r < RANK; ++r) res += bro[r] * tacc[r];
  out[(size_t)nrow * N_COLS + o] = res;
}

// ---------------- launch ----------------

extern "C" void kernel_launch(void* const* d_in, const int* in_sizes, int n_in,
                              void* d_out, int out_size, void* d_ws, size_t ws_size,
                              hipStream_t stream) {
  const float* x  = (const float*)d_in[0];
  const float* w  = (const float*)d_in[1];
  const float* A  = (const float*)d_in[2];
  const float* Bm = (const float*)d_in[3];
  float* out = (float*)d_out;

  const size_t need = ((size_t)N_ROWS * K_DIM + (size_t)N_COLS * K_DIM) * sizeof(unsigned short);
  if (ws_size < need) {
    dim3 grid(N_COLS / 256, N_ROWS);
    fallback_kernel<<<grid, 256, 0, stream>>>(x, w, A, Bm, out);
    return;
  }

  unsigned short* xb = (unsigned short*)d_ws;
  unsigned short* wb = xb + (size_t)N_ROWS * K_DIM;

  prep_kernel<<<XBLK + WBLK, 256, 0, stream>>>(x, w, A, Bm, xb, wb);

  const int grid_gemm = (N_ROWS / 256) * (N_COLS / 256);   // 512
  gemm_bf16_r11<<<grid_gemm, 512, 0, stream>>>(xb, wb, out);
}